// Round 1
// baseline (665.279 us; speedup 1.0000x reference)
//
#include <hip/hip_runtime.h>

#define ANUM 5
#define EPS 1e-10f

// ---------------------------------------------------------------------------
// Precompute kernel: builds the Cayley matrices Qr, Qt, Qy, then stores
//   ws[  0.. 63] = Qt
//   ws[ 64..127] = Q1 = Qt @ Qr   (so  Qt Tt Qt^T = (1-t) Qt X Qt^T + t Q1 Yt Q1^T)
//   ws[128..191] = Qy
//   ws[192..196] = w_r   ws[197..201] = w_s   ws[202] = t
// ---------------------------------------------------------------------------
__global__ void precompute_kernel(const float* __restrict__ kernel_r,
                                  const float* __restrict__ kernel_t,
                                  const float* __restrict__ kernel_phi,
                                  const float* __restrict__ kernel_s,
                                  const float* __restrict__ bias_r,
                                  const float* __restrict__ bias_t,
                                  const float* __restrict__ bias_y,
                                  float* __restrict__ ws) {
  __shared__ float sQ[3][64];  // Qr, Qt, Qy
  const int tid = threadIdx.x;
  if (tid < 3) {
    const float* bias = (tid == 0) ? bias_r : (tid == 1) ? bias_t : bias_y;

    float Bm[8][8];
#pragma unroll
    for (int a = 0; a < 8; ++a)
#pragma unroll
      for (int b = 0; b < 8; ++b) Bm[a][b] = 0.f;
#pragma unroll
    for (int a = 0; a < 7; ++a) {
#pragma unroll 8
      for (int c = 0; c < 7; ++c) {
        if (c <= a) {
          float v = bias[a + c];
          Bm[a + 1][c] = v;   // strictly lower
          Bm[c][a + 1] = -v;  // strictly upper
        }
      }
    }
    float A[8][8], C[8][8];
#pragma unroll
    for (int a = 0; a < 8; ++a)
#pragma unroll
      for (int b = 0; b < 8; ++b) {
        float id = (a == b) ? 1.f : 0.f;
        A[a][b] = id - Bm[a][b];
        C[a][b] = id + Bm[a][b];
      }
    // Gauss-Jordan (no pivoting: I - Bm has symmetric part I, stable)
#pragma unroll
    for (int p = 0; p < 8; ++p) {
      float inv = 1.f / A[p][p];
#pragma unroll
      for (int b = 0; b < 8; ++b) { A[p][b] *= inv; C[p][b] *= inv; }
#pragma unroll
      for (int r = 0; r < 8; ++r) {
        if (r == p) continue;
        float f = A[r][p];
#pragma unroll
        for (int b = 0; b < 8; ++b) { A[r][b] -= f * A[p][b]; C[r][b] -= f * C[p][b]; }
      }
    }
#pragma unroll
    for (int a = 0; a < 8; ++a)
#pragma unroll
      for (int b = 0; b < 8; ++b) sQ[tid][a * 8 + b] = C[a][b];
  } else if (tid == 3) {
    float sr = 0.f, ss = 0.f;
#pragma unroll
    for (int a = 0; a < ANUM; ++a) sr += kernel_r[a] * kernel_r[a];
#pragma unroll
    for (int a = 0; a < ANUM; ++a) ws[192 + a] = kernel_r[a] * kernel_r[a] / (sr + EPS);
#pragma unroll
    for (int a = 0; a < ANUM; ++a) ss += kernel_s[a] * kernel_s[a];
#pragma unroll
    for (int a = 0; a < ANUM; ++a) ws[197 + a] = kernel_s[a] * kernel_s[a] / (ss + EPS);
    float kt2 = kernel_t[0] * kernel_t[0];
    float kp2 = kernel_phi[0] * kernel_phi[0];
    ws[202] = kt2 / (kt2 + kp2 + EPS);
  }
  __syncthreads();
  // all 64 lanes: emit Qt, Q1 = Qt @ Qr, Qy
  const int i = tid >> 3, j = tid & 7;
  float acc = 0.f;
#pragma unroll
  for (int k = 0; k < 8; ++k) acc += sQ[1][i * 8 + k] * sQ[0][k * 8 + j];
  ws[tid]       = sQ[1][tid];   // Qt
  ws[64 + tid]  = acc;          // Q1
  ws[128 + tid] = sQ[2][tid];   // Qy
}

// ---------------------------------------------------------------------------
// Main kernel: one wave per batch element, lane = i*8+j of the 8x8 matrix.
// Congruence transform via wave-synchronous LDS (NO __syncthreads: each wave
// owns a private buffer; wave64 is lockstep, so ds_write -> s_waitcnt
// lgkmcnt(0) -> ds_read is fully ordered within the wave).
// Chain shortened: Ph = (1-t)*Qt X Qt^T + t*Q1 Yt Q1^T — the two transforms
// are independent and interleave in the LDS pipe. Global loads for the next
// iteration are issued before the current compute (no barriers => they stay
// in flight).
// ---------------------------------------------------------------------------
__device__ __forceinline__ float dot8(float4 a0, float4 a1, float4 b0, float4 b1) {
  return a0.x * b0.x + a0.y * b0.y + a0.z * b0.z + a0.w * b0.w +
         a1.x * b1.x + a1.y * b1.y + a1.z * b1.z + a1.w * b1.w;
}

#define LGKM0() asm volatile("s_waitcnt lgkmcnt(0)" ::: "memory")

__launch_bounds__(256, 4)
__global__ void spdsru_kernel(const float* __restrict__ x,
                              const float* __restrict__ states,
                              const float* __restrict__ ws,
                              float* __restrict__ out,        // B*64
                              float* __restrict__ out_state,  // B*320
                              int B, int ITER, int W) {
  __shared__ __align__(16) float lds[4][4][64];
  const int tid = threadIdx.x;
  const int lane = tid & 63;
  const int wv = tid >> 6;
  const int i = lane >> 3, j = lane & 7;
  float* b0 = lds[wv][0];
  float* b1 = lds[wv][1];
  float* b2 = lds[wv][2];
  float* b3 = lds[wv][3];

  // Q rows -> registers (amortized over ITER elements)
  const float4 Qti0 = *(const float4*)(ws + 0 + i * 8);
  const float4 Qti1 = *(const float4*)(ws + 0 + i * 8 + 4);
  const float4 Qtj0 = *(const float4*)(ws + 0 + j * 8);
  const float4 Qtj1 = *(const float4*)(ws + 0 + j * 8 + 4);
  const float4 Q1i0 = *(const float4*)(ws + 64 + i * 8);
  const float4 Q1i1 = *(const float4*)(ws + 64 + i * 8 + 4);
  const float4 Q1j0 = *(const float4*)(ws + 64 + j * 8);
  const float4 Q1j1 = *(const float4*)(ws + 64 + j * 8 + 4);
  const float4 Qyi0 = *(const float4*)(ws + 128 + i * 8);
  const float4 Qyi1 = *(const float4*)(ws + 128 + i * 8 + 4);
  const float4 Qyj0 = *(const float4*)(ws + 128 + j * 8);
  const float4 Qyj1 = *(const float4*)(ws + 128 + j * 8 + 4);
  const float wr0 = ws[192], wr1 = ws[193], wr2 = ws[194], wr3 = ws[195], wr4 = ws[196];
  const float ks0 = ws[197], ks1 = ws[198], ks2 = ws[199], ks3 = ws[200], ks4 = ws[201];
  const float tg = ws[202];

  const int wave = (blockIdx.x * 256 + tid) >> 6;

  int b = wave;
  float X = 0.f, M0 = 0.f, M1 = 0.f, M2 = 0.f, M3 = 0.f, M4 = 0.f;
  if (b < B) {
    const float* S = states + (size_t)b * 320;
    X  = x[(size_t)b * 64 + lane];
    M0 = S[0 * 64 + lane];
    M1 = S[1 * 64 + lane];
    M2 = S[2 * 64 + lane];
    M3 = S[3 * 64 + lane];
    M4 = S[4 * 64 + lane];
  }

  for (int it = 0; it < ITER; ++it) {
    const int bn = b + W;
    // ---- prefetch next element (stays in flight: no barriers anywhere) ----
    float Xn = 0.f, N0 = 0.f, N1 = 0.f, N2 = 0.f, N3 = 0.f, N4 = 0.f;
    if (it + 1 < ITER && bn < B) {
      const float* Sn = states + (size_t)bn * 320;
      Xn = x[(size_t)bn * 64 + lane];
      N0 = Sn[0 * 64 + lane];
      N1 = Sn[1 * 64 + lane];
      N2 = Sn[2 * 64 + lane];
      N3 = Sn[3 * 64 + lane];
      N4 = Sn[4 * 64 + lane];
    }

    // ---- Yt = nus(M, w_r) ----
    const float Yt = wr0 * M0 + wr1 * M1 + wr2 * M2 + wr3 * M3 + wr4 * M4;

    // ---- parallel transforms: A = Qt X Qt^T,  Bv = Q1 Yt Q1^T ----
    b0[lane] = X;
    b2[lane] = Yt;
    LGKM0();
    {
      float4 xr0 = *(const float4*)(b0 + i * 8);
      float4 xr1 = *(const float4*)(b0 + i * 8 + 4);
      float4 yr0 = *(const float4*)(b2 + i * 8);
      float4 yr1 = *(const float4*)(b2 + i * 8 + 4);
      float vx = dot8(xr0, xr1, Qtj0, Qtj1);
      float vy = dot8(yr0, yr1, Q1j0, Q1j1);
      b1[j * 8 + i] = vx;  // transposed store
      b3[j * 8 + i] = vy;
    }
    LGKM0();
    float XT, YT;
    {
      float4 xc0 = *(const float4*)(b1 + j * 8);
      float4 xc1 = *(const float4*)(b1 + j * 8 + 4);
      float4 yc0 = *(const float4*)(b3 + j * 8);
      float4 yc1 = *(const float4*)(b3 + j * 8 + 4);
      XT = dot8(xc0, xc1, Qti0, Qti1);
      YT = dot8(yc0, yc1, Q1i0, Q1i1);
    }
    const float Ph = (1.f - tg) * XT + tg * YT;

    // ---- Mt = (1-alpha) Mt_1 + alpha Phit ----
    M0 = (1.0f - 0.01f) * M0 + 0.01f * Ph;
    M1 = (1.0f - 0.25f) * M1 + 0.25f * Ph;
    M2 = (1.0f - 0.5f)  * M2 + 0.5f  * Ph;
    M3 = (1.0f - 0.9f)  * M3 + 0.9f  * Ph;
    M4 = (1.0f - 0.99f) * M4 + 0.99f * Ph;

    // state store can issue now, overlapping the last transform
    if (b < B) {
      float* SO = out_state + (size_t)b * 320;
      SO[0 * 64 + lane] = M0;
      SO[1 * 64 + lane] = M1;
      SO[2 * 64 + lane] = M2;
      SO[3 * 64 + lane] = M3;
      SO[4 * 64 + lane] = M4;
    }

    // ---- St = nus(Mt, w_s); Ot = Qy St Qy^T ----
    const float St = ks0 * M0 + ks1 * M1 + ks2 * M2 + ks3 * M3 + ks4 * M4;
    b0[lane] = St;
    LGKM0();
    {
      float4 r0 = *(const float4*)(b0 + i * 8);
      float4 r1 = *(const float4*)(b0 + i * 8 + 4);
      float v = dot8(r0, r1, Qyj0, Qyj1);
      b1[j * 8 + i] = v;
    }
    LGKM0();
    float Ot;
    {
      float4 c0 = *(const float4*)(b1 + j * 8);
      float4 c1 = *(const float4*)(b1 + j * 8 + 4);
      Ot = dot8(c0, c1, Qyi0, Qyi1);
    }
    if (b < B) out[(size_t)b * 64 + lane] = Ot;

    // rotate prefetched element in
    X = Xn; M0 = N0; M1 = N1; M2 = N2; M3 = N3; M4 = N4;
    b = bn;
  }
}

extern "C" void kernel_launch(void* const* d_in, const int* in_sizes, int n_in,
                              void* d_out, int out_size, void* d_ws, size_t ws_size,
                              hipStream_t stream) {
  const float* x          = (const float*)d_in[0];
  const float* states     = (const float*)d_in[1];
  const float* kernel_r   = (const float*)d_in[2];
  const float* kernel_t   = (const float*)d_in[3];
  const float* kernel_phi = (const float*)d_in[4];
  const float* kernel_s   = (const float*)d_in[5];
  const float* bias_r     = (const float*)d_in[6];
  const float* bias_t     = (const float*)d_in[7];
  const float* bias_y     = (const float*)d_in[8];
  float* ws = (float*)d_ws;
  float* out = (float*)d_out;

  const int B = in_sizes[0] / 64;
  float* out_state = out + (size_t)B * 64;

  precompute_kernel<<<1, 64, 0, stream>>>(kernel_r, kernel_t, kernel_phi, kernel_s,
                                          bias_r, bias_t, bias_y, ws);

  const int blocks = 2048;           // 8192 waves; B=262144 -> 32 elements/wave
  const int W = blocks * 4;          // waves in grid
  const int ITER = (B + W - 1) / W;
  spdsru_kernel<<<blocks, 256, 0, stream>>>(x, states, ws, out, out_state, B, ITER, W);
}